// Round 3
// baseline (1048.199 us; speedup 1.0000x reference)
//
#include <hip/hip_runtime.h>
#include <hip/hip_bf16.h>
#include <math.h>

typedef __bf16 bf16_t;
typedef __bf16 bf16x8 __attribute__((ext_vector_type(8)));
typedef float f32x4 __attribute__((ext_vector_type(4)));

#define SCALE_F 0.08838834764831845f  // 1/sqrt(128)
#define SMAX_F 14.0f                  // fixed softmax max: score <= sqrt(128)=11.32 (+bf16 margin)

// async global->LDS, 16B per lane; LDS dest = wave-uniform base + lane*16
#define GLOAD_LDS16(gp, lp)                                              \
    __builtin_amdgcn_global_load_lds(                                    \
        (const __attribute__((address_space(1))) void*)(gp),             \
        (__attribute__((address_space(3))) void*)(lp), 16, 0, 0)

// ---------------- fp32 -> bf16 convert (vectorized) ----------------
__global__ void k_convert(const float* __restrict__ in, bf16_t* __restrict__ out, int n) {
    int i = (blockIdx.x * 256 + threadIdx.x) * 4;
    if (i >= n) return;
    float4 f = *(const float4*)(in + i);
    out[i + 0] = (bf16_t)f.x;
    out[i + 1] = (bf16_t)f.y;
    out[i + 2] = (bf16_t)f.z;
    out[i + 3] = (bf16_t)f.w;
}

// ---------------- transpose + convert: w[K][N] -> wt[N][K] bf16 ----------------
__global__ void k_transpose(const float* __restrict__ w, bf16_t* __restrict__ wt, int K, int N) {
    __shared__ float tile[32][33];
    int n0 = blockIdx.x * 32, k0 = blockIdx.y * 32;
    int tx = threadIdx.x & 31, ty = threadIdx.x >> 5;  // 32x8
#pragma unroll
    for (int i = 0; i < 32; i += 8)
        tile[ty + i][tx] = w[(size_t)(k0 + ty + i) * N + (n0 + tx)];
    __syncthreads();
#pragma unroll
    for (int i = 0; i < 32; i += 8)
        wt[(size_t)(n0 + ty + i) * K + (k0 + tx)] = (bf16_t)tile[tx][ty + i];
}

// ---------------- rope tables ----------------
__global__ void k_rope_tables(float* __restrict__ cosT, float* __restrict__ sinT) {
    int idx = blockIdx.x * 256 + threadIdx.x;  // t*64 + i
    int t = idx >> 6, i = idx & 63;
    float invf = powf(10000.f, -(float)(i & 31) / 32.f);
    float ang = (float)t * invf;
    float s, c;
    sincosf(ang, &s, &c);
    cosT[idx] = c;
    sinT[idx] = s;
}

// ---------------- row-wise rmsnorm, in-place bf16, fp32 gain ----------------
__global__ void k_rmsnorm(bf16_t* __restrict__ x, const float* __restrict__ g, int C) {
    bf16_t* p = x + (size_t)blockIdx.x * C;
    float ss = 0.f;
    for (int i = threadIdx.x; i < C; i += 256) {
        float v = (float)p[i];
        ss += v * v;
    }
#pragma unroll
    for (int m = 32; m; m >>= 1) ss += __shfl_xor(ss, m);
    __shared__ float red[4];
    if ((threadIdx.x & 63) == 0) red[threadIdx.x >> 6] = ss;
    __syncthreads();
    float tot = red[0] + red[1] + red[2] + red[3];
    float scale = rsqrtf(tot / (float)C + 1e-6f);
    for (int i = threadIdx.x; i < C; i += 256)
        p[i] = (bf16_t)((float)p[i] * scale * g[i]);
}

// ---------------- GEMM (m97 structure): C[M][N] = A[M][K] @ Bt[N][K]^T ----------------
template <int OUTF32>
__global__ __launch_bounds__(256) void k_gemm(const bf16_t* __restrict__ A,
                                              const bf16_t* __restrict__ Bt,
                                              void* __restrict__ Cp, int M, int N, int K,
                                              size_t sA, size_t sB, size_t sC) {
    __shared__ bf16_t As[128 * 32];
    __shared__ bf16_t Bs[128 * 32];
    A += (size_t)blockIdx.z * sA;
    Bt += (size_t)blockIdx.z * sB;
    const size_t coff = (size_t)blockIdx.z * sC;
    const int bm = blockIdx.y * 128, bn = blockIdx.x * 128;
    const int tid = threadIdx.x, lane = tid & 63, wv = tid >> 6;
    const int quad = lane >> 4, l16 = lane & 15;
    const int wm = (wv >> 1) * 64, wn = (wv & 1) * 64;
    f32x4 acc[4][4] = {};
    const int sr0 = wv * 32 + (lane >> 2);
    const int scc = (lane & 3) * 8;
    bf16_t* ldsA0 = As + (wv * 2) * 512;
    bf16_t* ldsA1 = As + (wv * 2 + 1) * 512;
    bf16_t* ldsB0 = Bs + (wv * 2) * 512;
    bf16_t* ldsB1 = Bs + (wv * 2 + 1) * 512;
    const bool bok0 = (bn + sr0) < N;
    const bool bok1 = (bn + sr0 + 16) < N;
    for (int k0 = 0; k0 < K; k0 += 32) {
        const bf16_t* gA = A + (size_t)(bm + sr0) * K + k0 + scc;
        const bf16_t* gB = Bt + (size_t)(bn + sr0) * K + k0 + scc;
        GLOAD_LDS16(gA, ldsA0);
        GLOAD_LDS16(gA + (size_t)16 * K, ldsA1);
        if (bok0) GLOAD_LDS16(gB, ldsB0);
        if (bok1) GLOAD_LDS16(gB + (size_t)16 * K, ldsB1);
        __syncthreads();
        bf16x8 af[4], bfr[4];
#pragma unroll
        for (int mi = 0; mi < 4; ++mi)
            af[mi] = *(bf16x8*)(As + (wm + mi * 16 + l16) * 32 + quad * 8);
#pragma unroll
        for (int ni = 0; ni < 4; ++ni)
            bfr[ni] = *(bf16x8*)(Bs + (wn + ni * 16 + l16) * 32 + quad * 8);
#pragma unroll
        for (int mi = 0; mi < 4; ++mi)
#pragma unroll
            for (int ni = 0; ni < 4; ++ni)
                acc[mi][ni] =
                    __builtin_amdgcn_mfma_f32_16x16x32_bf16(af[mi], bfr[ni], acc[mi][ni], 0, 0, 0);
        __syncthreads();
    }
#pragma unroll
    for (int mi = 0; mi < 4; ++mi)
#pragma unroll
        for (int ni = 0; ni < 4; ++ni)
#pragma unroll
            for (int r = 0; r < 4; ++r) {
                int row = bm + wm + mi * 16 + quad * 4 + r;
                int col = bn + wn + ni * 16 + l16;
                if (col < N) {
                    if constexpr (OUTF32)
                        ((float*)Cp)[coff + (size_t)row * N + col] = acc[mi][ni][r];
                    else
                        ((bf16_t*)Cp)[coff + (size_t)row * N + col] = (bf16_t)acc[mi][ni][r];
                }
            }
}

// ---------------- build q ----------------
__global__ void k_build_q(bf16_t* __restrict__ q, const float* __restrict__ g,
                          const float* __restrict__ cosT, const float* __restrict__ sinT) {
    int wid = blockIdx.x * 4 + (threadIdx.x >> 6);
    int lane = threadIdx.x & 63;
    int row = wid >> 4, h = wid & 15;
    int t = row & 2047;
    bf16_t* p = q + (size_t)row * 2048 + h * 128;
    float x0 = (float)p[lane];
    float x1 = (float)p[64 + lane];
    float xp = (float)p[64 + (lane ^ 32)];
    float c = cosT[t * 64 + lane], s = sinT[t * 64 + lane];
    float rot = (lane < 32) ? -xp : xp;
    float y1 = x1 * c + rot * s;
    float ss = x0 * x0 + y1 * y1;
#pragma unroll
    for (int m = 32; m; m >>= 1) ss += __shfl_xor(ss, m);
    float scale = rsqrtf(ss / 128.f + 1e-6f);
    p[lane] = (bf16_t)(x0 * scale * g[lane]);
    p[64 + lane] = (bf16_t)(y1 * scale * g[64 + lane]);
}

// ---------------- build k ----------------
__global__ void k_build_k(const bf16_t* __restrict__ knope, const bf16_t* __restrict__ krope,
                          bf16_t* __restrict__ kout, const float* __restrict__ g,
                          const float* __restrict__ cosT, const float* __restrict__ sinT) {
    int wid = blockIdx.x * 4 + (threadIdx.x >> 6);
    int lane = threadIdx.x & 63;
    int row = wid >> 4, h = wid & 15;
    int t = row & 2047;
    float x0 = (float)knope[(size_t)row * 1024 + h * 64 + lane];
    float x1 = (float)krope[(size_t)row * 64 + lane];
    float xp = (float)krope[(size_t)row * 64 + (lane ^ 32)];
    float c = cosT[t * 64 + lane], s = sinT[t * 64 + lane];
    float rot = (lane < 32) ? -xp : xp;
    float y1 = x1 * c + rot * s;
    float ss = x0 * x0 + y1 * y1;
#pragma unroll
    for (int m = 32; m; m >>= 1) ss += __shfl_xor(ss, m);
    float scale = rsqrtf(ss / 128.f + 1e-6f);
    bf16_t* p = kout + (size_t)row * 2048 + h * 128;
    p[lane] = (bf16_t)(x0 * scale * g[lane]);
    p[64 + lane] = (bf16_t)(y1 * scale * g[64 + lane]);
}

// ---------------- flash attention + silu(gate), fixed-max softmax ----------------
// grid (T/128, B*H), 512 threads = 8 waves = 4 row-groups (32 q-rows) x 2-way split.
// Pair (wt,part): QK^T splits the s-axis, PV splits the d-axis -> each LDS B-frag read
// feeds 2 MFMAs. All LDS tiles unpadded with the m214 XOR swizzle
//   elem(row,col) -> row*RS + (col ^ ((row&7)<<3))
// applied on BOTH write and read side (reg-staged, so both sides can swizzle). This
// breaks the 8-way b128 column-read conflicts that padding cannot fix.
// q,k,gate,o layout [(b*2048+pos)*2048 + h*128 + d]; vT layout [b][h*128+d][t].
__global__ __launch_bounds__(512, 4) void k_attn(const bf16_t* __restrict__ q,
                                                 const bf16_t* __restrict__ k,
                                                 const bf16_t* __restrict__ vT,
                                                 const bf16_t* __restrict__ gate,
                                                 bf16_t* __restrict__ o) {
    __shared__ bf16_t Ks[64 * 128];   // [s][128 d], swizzled   16 KB
    __shared__ bf16_t Vt[128 * 64];   // [d][64 s], swizzled    16 KB
    __shared__ bf16_t Ps[128 * 64];   // [t][64 s], swizzled    16 KB
    const int qb = (int)gridDim.x - 1 - (int)blockIdx.x;  // long blocks first
    const int bh = blockIdx.y;
    const int b = bh >> 4, h = bh & 15;
    const int t0 = qb * 128;
    const int tid = threadIdx.x, lane = tid & 63, wv = tid >> 6;  // wv 0..7
    const int quad = lane >> 4, l16 = lane & 15;
    const int wt = wv >> 1;          // row-group 0..3
    const int part = wv & 1;         // s-half (QK) / d-half (PV)
    const int wrow = t0 + wt * 32;   // row-group's first q row
    const int swl = (l16 & 7) << 3;  // read-side swizzle (rows read per-lane are == l16 mod 8)

    // Q fragments in registers: 2 row-tiles x 4 k-slices
    bf16x8 aq[2][4];
#pragma unroll
    for (int mi = 0; mi < 2; ++mi) {
        const bf16_t* qp =
            q + ((size_t)(b * 2048 + wrow + mi * 16 + l16)) * 2048 + h * 128 + quad * 8;
#pragma unroll
        for (int kk = 0; kk < 4; ++kk) aq[mi][kk] = *(const bf16x8*)(qp + kk * 32);
    }
    f32x4 oacc[2][4] = {};           // [row-tile][d-tile within this wave's 64-d half]
    float l_i[2][4] = {};            // partial softmax denom over this wave's s-half

    const bf16_t* vbase = vT + ((size_t)b * 2048 + (size_t)h * 128) * 2048;
    const bf16_t* kbase = k + ((size_t)b * 2048) * 2048 + h * 128;

    // staging indices (512 threads); dst offsets are pre-swizzled
    const int krow = tid >> 4;                                   // 0..31 (+32)
    const int kcol = (tid & 15) * 8;
    const int kdst = krow * 128 + (kcol ^ ((krow & 7) << 3));    // (krow+32)&7 == krow&7
    const int vrow = tid >> 3;                                   // 0..63 (+64)
    const int vcol = (tid & 7) * 8;
    const int vdst = vrow * 64 + (vcol ^ ((vrow & 7) << 3));     // (vrow+64)&7 == vrow&7

    const int nkb = 2 * qb + 2;  // key tiles 0 .. 2qb+1
    bf16x8 kreg0, kreg1, vreg0, vreg1;
    {
        kreg0 = *(const bf16x8*)(kbase + (size_t)krow * 2048 + kcol);
        kreg1 = *(const bf16x8*)(kbase + (size_t)(krow + 32) * 2048 + kcol);
        vreg0 = *(const bf16x8*)(vbase + (size_t)vrow * 2048 + vcol);
        vreg1 = *(const bf16x8*)(vbase + (size_t)(vrow + 64) * 2048 + vcol);
    }
    for (int kb = 0; kb < nkb; ++kb) {
        const int s0 = kb * 64;
        __syncthreads();  // prev iter done reading LDS
        *(bf16x8*)(Ks + kdst) = kreg0;
        *(bf16x8*)(Ks + kdst + 32 * 128) = kreg1;
        *(bf16x8*)(Vt + vdst) = vreg0;
        *(bf16x8*)(Vt + vdst + 64 * 64) = vreg1;
        __syncthreads();
        if (kb + 1 < nkb) {  // prefetch next tile; latency overlaps compute below
            const int sn = s0 + 64;
            kreg0 = *(const bf16x8*)(kbase + (size_t)(sn + krow) * 2048 + kcol);
            kreg1 = *(const bf16x8*)(kbase + (size_t)(sn + krow + 32) * 2048 + kcol);
            vreg0 = *(const bf16x8*)(vbase + (size_t)vrow * 2048 + sn + vcol);
            vreg1 = *(const bf16x8*)(vbase + (size_t)(vrow + 64) * 2048 + sn + vcol);
        }
        const bool active = (s0 <= wrow + 31);  // pair-uniform
        if (active) {
            // S = Q K^T : this wave's 32x32 quarter (s-half = part), ni-outer so only
            // one f32x4 pair is live at a time (register relief)
#pragma unroll
            for (int ni = 0; ni < 2; ++ni) {
                f32x4 sc2[2] = {{0.f, 0.f, 0.f, 0.f}, {0.f, 0.f, 0.f, 0.f}};
#pragma unroll
                for (int kk = 0; kk < 4; ++kk) {
                    bf16x8 bk = *(bf16x8*)(Ks + (part * 32 + ni * 16 + l16) * 128 +
                                           ((kk * 32 + quad * 8) ^ swl));
                    sc2[0] = __builtin_amdgcn_mfma_f32_16x16x32_bf16(aq[0][kk], bk, sc2[0], 0, 0, 0);
                    sc2[1] = __builtin_amdgcn_mfma_f32_16x16x32_bf16(aq[1][kk], bk, sc2[1], 0, 0, 0);
                }
                // fixed-max softmax: p = exp(s*SCALE - SMAX); no per-iter reductions
                const int scol = s0 + part * 32 + ni * 16 + l16;
#pragma unroll
                for (int mi = 0; mi < 2; ++mi) {
                    const int trowb = wrow + mi * 16 + quad * 4;
                    const bool dg = (s0 + part * 32 + 31) > trowb;
                    const int prow0 = wt * 32 + mi * 16 + quad * 4;
#pragma unroll
                    for (int r2 = 0; r2 < 4; ++r2) {
                        float pv = __expf(sc2[mi][r2] * SCALE_F - SMAX_F);
                        if (dg && scol > trowb + r2) pv = 0.f;
                        l_i[mi][r2] += pv;
                        const int pr = prow0 + r2;
                        Ps[pr * 64 + ((part * 32 + ni * 16 + l16) ^ ((pr & 7) << 3))] =
                            (bf16_t)pv;
                    }
                }
            }
        }
        __syncthreads();  // both halves of P ready (pair exchange)
        if (active) {
            // O += P V : full s range, this wave's 64-d half
#pragma unroll
            for (int kk = 0; kk < 2; ++kk) {
                bf16x8 ap[2];
#pragma unroll
                for (int mi = 0; mi < 2; ++mi)
                    ap[mi] = *(bf16x8*)(Ps + (wt * 32 + mi * 16 + l16) * 64 +
                                        ((kk * 32 + quad * 8) ^ swl));
#pragma unroll
                for (int nd = 0; nd < 4; ++nd) {
                    bf16x8 bv = *(bf16x8*)(Vt + (part * 64 + nd * 16 + l16) * 64 +
                                           ((kk * 32 + quad * 8) ^ swl));
#pragma unroll
                    for (int mi = 0; mi < 2; ++mi)
                        oacc[mi][nd] = __builtin_amdgcn_mfma_f32_16x16x32_bf16(ap[mi], bv,
                                                                               oacc[mi][nd], 0, 0, 0);
                }
            }
        }
    }
    // reduce partial l over the 16 lanes holding each row
#pragma unroll
    for (int m = 8; m; m >>= 1)
#pragma unroll
        for (int mi = 0; mi < 2; ++mi)
#pragma unroll
            for (int r2 = 0; r2 < 4; ++r2) l_i[mi][r2] += __shfl_xor(l_i[mi][r2], m);
    // exchange l between the s-halves via LDS (Ps is dead now)
    __syncthreads();
    float* lbuf = (float*)Ps;  // [2][128]
    if (l16 == 0) {
#pragma unroll
        for (int mi = 0; mi < 2; ++mi)
#pragma unroll
            for (int r2 = 0; r2 < 4; ++r2)
                lbuf[part * 128 + wt * 32 + mi * 16 + quad * 4 + r2] = l_i[mi][r2];
    }
    __syncthreads();
    float rl[2][4];
#pragma unroll
    for (int mi = 0; mi < 2; ++mi)
#pragma unroll
        for (int r2 = 0; r2 < 4; ++r2) {
            int row = wt * 32 + mi * 16 + quad * 4 + r2;
            rl[mi][r2] = 1.f / (lbuf[row] + lbuf[128 + row]);
        }
    // epilogue: normalize, silu(gate), store (this wave's 64-d half)
#pragma unroll
    for (int nd = 0; nd < 4; ++nd) {
        int d = part * 64 + nd * 16 + l16;
#pragma unroll
        for (int mi = 0; mi < 2; ++mi)
#pragma unroll
            for (int r2 = 0; r2 < 4; ++r2) {
                int trow = wrow + mi * 16 + quad * 4 + r2;
                size_t gi = ((size_t)(b * 2048 + trow)) * 2048 + h * 128 + d;
                float gt = (float)gate[gi];
                float sg = gt / (1.f + __expf(-gt));
                o[gi] = (bf16_t)((oacc[mi][nd][r2] * rl[mi][r2]) * sg);
            }
    }
}

extern "C" void kernel_launch(void* const* d_in, const int* in_sizes, int n_in,
                              void* d_out, int out_size, void* d_ws, size_t ws_size,
                              hipStream_t stream) {
    const float* x         = (const float*)d_in[0];
    const float* w_q_down  = (const float*)d_in[1];
    const float* g_q_down  = (const float*)d_in[2];
    const float* w_q_up    = (const float*)d_in[3];
    const float* w_kv_down = (const float*)d_in[4];
    const float* g_kv_down = (const float*)d_in[5];
    const float* w_k_up    = (const float*)d_in[6];
    const float* w_v_up    = (const float*)d_in[7];
    const float* w_k_rope  = (const float*)d_in[8];
    const float* g_q       = (const float*)d_in[9];
    const float* g_k       = (const float*)d_in[10];
    const float* w_gate    = (const float*)d_in[11];
    const float* w_o       = (const float*)d_in[12];
    float* out = (float*)d_out;

    char* base = (char*)d_ws;
    size_t off = 0;
    auto alloc = [&](size_t bytes) -> void* {
        void* p = base + off;
        off = (off + bytes + 255) & ~(size_t)255;
        return p;
    };
    const size_t MT = 8192;  // B*T
    bf16_t* xb     = (bf16_t*)alloc(MT * 2048 * 2);
    bf16_t* wqd_t  = (bf16_t*)alloc((size_t)1024 * 2048 * 2);
    bf16_t* wqu_t  = (bf16_t*)alloc((size_t)2048 * 1024 * 2);
    bf16_t* wkvd_t = (bf16_t*)alloc((size_t)512 * 2048 * 2);
    bf16_t* wku_t  = (bf16_t*)alloc((size_t)1024 * 512 * 2);
    bf16_t* wvu_t  = (bf16_t*)alloc((size_t)2048 * 512 * 2);
    bf16_t* wkr_t  = (bf16_t*)alloc((size_t)64 * 2048 * 2);
    bf16_t* wg_t   = (bf16_t*)alloc((size_t)2048 * 2048 * 2);
    bf16_t* wo_t   = (bf16_t*)alloc((size_t)2048 * 2048 * 2);
    bf16_t* qc     = (bf16_t*)alloc(MT * 1024 * 2);
    bf16_t* ckv    = (bf16_t*)alloc(MT * 512 * 2);
    bf16_t* krope  = (bf16_t*)alloc(MT * 64 * 2);
    bf16_t* vT     = (bf16_t*)alloc(MT * 2048 * 2);  // [b][h*128+d][t]
    bf16_t* gbuf   = (bf16_t*)alloc(MT * 2048 * 2);
    float* cosT    = (float*)alloc((size_t)2048 * 64 * 4);
    float* sinT    = (float*)alloc((size_t)2048 * 64 * 4);
    bf16_t* knope = qc;              // qc dead after q_up GEMM
    bf16_t* qbuf  = (bf16_t*)d_out;  // d_out scratch until final GEMM
    bf16_t* kbuf  = (bf16_t*)d_out + MT * 2048;
    bf16_t* obuf  = xb;              // xb dead after all x@W GEMMs

    k_convert<<<dim3(16384), dim3(256), 0, stream>>>(x, xb, 16777216);
    k_transpose<<<dim3(32, 64), 256, 0, stream>>>(w_q_down, wqd_t, 2048, 1024);
    k_transpose<<<dim3(64, 32), 256, 0, stream>>>(w_q_up, wqu_t, 1024, 2048);
    k_transpose<<<dim3(16, 64), 256, 0, stream>>>(w_kv_down, wkvd_t, 2048, 512);
    k_transpose<<<dim3(32, 16), 256, 0, stream>>>(w_k_up, wku_t, 512, 1024);
    k_transpose<<<dim3(64, 16), 256, 0, stream>>>(w_v_up, wvu_t, 512, 2048);
    k_transpose<<<dim3(2, 64), 256, 0, stream>>>(w_k_rope, wkr_t, 2048, 64);
    k_transpose<<<dim3(64, 64), 256, 0, stream>>>(w_gate, wg_t, 2048, 2048);
    k_transpose<<<dim3(64, 64), 256, 0, stream>>>(w_o, wo_t, 2048, 2048);
    k_rope_tables<<<dim3(512), 256, 0, stream>>>(cosT, sinT);
    // q path
    k_gemm<0><<<dim3(8, 64), 256, 0, stream>>>(xb, wqd_t, qc, 8192, 1024, 2048, 0, 0, 0);
    k_rmsnorm<<<dim3(8192), 256, 0, stream>>>(qc, g_q_down, 1024);
    k_gemm<0><<<dim3(16, 64), 256, 0, stream>>>(qc, wqu_t, qbuf, 8192, 2048, 1024, 0, 0, 0);
    // kv path
    k_gemm<0><<<dim3(4, 64), 256, 0, stream>>>(xb, wkvd_t, ckv, 8192, 512, 2048, 0, 0, 0);
    k_rmsnorm<<<dim3(8192), 256, 0, stream>>>(ckv, g_kv_down, 512);
    k_gemm<0><<<dim3(8, 64), 256, 0, stream>>>(ckv, wku_t, knope, 8192, 1024, 512, 0, 0, 0);
    // V^T per batch: vT_b[hd][t] = wvu_t[hd][k] · ckv_b[t][k]
    k_gemm<0><<<dim3(16, 16, 4), 256, 0, stream>>>(wvu_t, ckv, vT, 2048, 2048, 512,
                                                   0, (size_t)2048 * 512, (size_t)2048 * 2048);
    k_gemm<0><<<dim3(1, 64), 256, 0, stream>>>(xb, wkr_t, krope, 8192, 64, 2048, 0, 0, 0);
    // gate
    k_gemm<0><<<dim3(16, 64), 256, 0, stream>>>(xb, wg_t, gbuf, 8192, 2048, 2048, 0, 0, 0);
    // assemble q/k
    k_build_q<<<dim3(32768), 256, 0, stream>>>(qbuf, g_q, cosT, sinT);
    k_build_k<<<dim3(32768), 256, 0, stream>>>(knope, krope, kbuf, g_k, cosT, sinT);
    // attention + silu(gate)
    k_attn<<<dim3(16, 64), 512, 0, stream>>>(qbuf, kbuf, vT, gbuf, obuf);
    // output projection
    k_gemm<1><<<dim3(16, 64), 256, 0, stream>>>(obuf, wo_t, out, 8192, 2048, 2048, 0, 0, 0);
}

// Round 4
// 898.262 us; speedup vs baseline: 1.1669x; 1.1669x over previous
//
#include <hip/hip_runtime.h>
#include <hip/hip_bf16.h>
#include <math.h>

typedef __bf16 bf16_t;
typedef __bf16 bf16x8 __attribute__((ext_vector_type(8)));
typedef float f32x4 __attribute__((ext_vector_type(4)));

#define SCALE_F 0.08838834764831845f  // 1/sqrt(128)
#define SMAX_F 14.0f                  // fixed softmax max: score <= sqrt(128)=11.32 (+bf16 margin)

// async global->LDS, 16B per lane; LDS dest = wave-uniform base + lane*16
#define GLOAD_LDS16(gp, lp)                                              \
    __builtin_amdgcn_global_load_lds(                                    \
        (const __attribute__((address_space(1))) void*)(gp),             \
        (__attribute__((address_space(3))) void*)(lp), 16, 0, 0)

// ---------------- fp32 -> bf16 convert (vectorized) ----------------
__global__ void k_convert(const float* __restrict__ in, bf16_t* __restrict__ out, int n) {
    int i = (blockIdx.x * 256 + threadIdx.x) * 4;
    if (i >= n) return;
    float4 f = *(const float4*)(in + i);
    out[i + 0] = (bf16_t)f.x;
    out[i + 1] = (bf16_t)f.y;
    out[i + 2] = (bf16_t)f.z;
    out[i + 3] = (bf16_t)f.w;
}

// ---------------- transpose + convert: w[K][N] -> wt[N][K] bf16 ----------------
__global__ void k_transpose(const float* __restrict__ w, bf16_t* __restrict__ wt, int K, int N) {
    __shared__ float tile[32][33];
    int n0 = blockIdx.x * 32, k0 = blockIdx.y * 32;
    int tx = threadIdx.x & 31, ty = threadIdx.x >> 5;  // 32x8
#pragma unroll
    for (int i = 0; i < 32; i += 8)
        tile[ty + i][tx] = w[(size_t)(k0 + ty + i) * N + (n0 + tx)];
    __syncthreads();
#pragma unroll
    for (int i = 0; i < 32; i += 8)
        wt[(size_t)(n0 + ty + i) * K + (k0 + tx)] = (bf16_t)tile[tx][ty + i];
}

// ---------------- rope tables ----------------
__global__ void k_rope_tables(float* __restrict__ cosT, float* __restrict__ sinT) {
    int idx = blockIdx.x * 256 + threadIdx.x;  // t*64 + i
    int t = idx >> 6, i = idx & 63;
    float invf = powf(10000.f, -(float)(i & 31) / 32.f);
    float ang = (float)t * invf;
    float s, c;
    sincosf(ang, &s, &c);
    cosT[idx] = c;
    sinT[idx] = s;
}

// ---------------- row-wise rmsnorm, in-place bf16, fp32 gain ----------------
__global__ void k_rmsnorm(bf16_t* __restrict__ x, const float* __restrict__ g, int C) {
    bf16_t* p = x + (size_t)blockIdx.x * C;
    float ss = 0.f;
    for (int i = threadIdx.x; i < C; i += 256) {
        float v = (float)p[i];
        ss += v * v;
    }
#pragma unroll
    for (int m = 32; m; m >>= 1) ss += __shfl_xor(ss, m);
    __shared__ float red[4];
    if ((threadIdx.x & 63) == 0) red[threadIdx.x >> 6] = ss;
    __syncthreads();
    float tot = red[0] + red[1] + red[2] + red[3];
    float scale = rsqrtf(tot / (float)C + 1e-6f);
    for (int i = threadIdx.x; i < C; i += 256)
        p[i] = (bf16_t)((float)p[i] * scale * g[i]);
}

// ---------------- GEMM (m97 structure): C[M][N] = A[M][K] @ Bt[N][K]^T ----------------
template <int OUTF32>
__global__ __launch_bounds__(256) void k_gemm(const bf16_t* __restrict__ A,
                                              const bf16_t* __restrict__ Bt,
                                              void* __restrict__ Cp, int M, int N, int K,
                                              size_t sA, size_t sB, size_t sC) {
    __shared__ bf16_t As[128 * 32];
    __shared__ bf16_t Bs[128 * 32];
    A += (size_t)blockIdx.z * sA;
    Bt += (size_t)blockIdx.z * sB;
    const size_t coff = (size_t)blockIdx.z * sC;
    const int bm = blockIdx.y * 128, bn = blockIdx.x * 128;
    const int tid = threadIdx.x, lane = tid & 63, wv = tid >> 6;
    const int quad = lane >> 4, l16 = lane & 15;
    const int wm = (wv >> 1) * 64, wn = (wv & 1) * 64;
    f32x4 acc[4][4] = {};
    const int sr0 = wv * 32 + (lane >> 2);
    const int scc = (lane & 3) * 8;
    bf16_t* ldsA0 = As + (wv * 2) * 512;
    bf16_t* ldsA1 = As + (wv * 2 + 1) * 512;
    bf16_t* ldsB0 = Bs + (wv * 2) * 512;
    bf16_t* ldsB1 = Bs + (wv * 2 + 1) * 512;
    const bool bok0 = (bn + sr0) < N;
    const bool bok1 = (bn + sr0 + 16) < N;
    for (int k0 = 0; k0 < K; k0 += 32) {
        const bf16_t* gA = A + (size_t)(bm + sr0) * K + k0 + scc;
        const bf16_t* gB = Bt + (size_t)(bn + sr0) * K + k0 + scc;
        GLOAD_LDS16(gA, ldsA0);
        GLOAD_LDS16(gA + (size_t)16 * K, ldsA1);
        if (bok0) GLOAD_LDS16(gB, ldsB0);
        if (bok1) GLOAD_LDS16(gB + (size_t)16 * K, ldsB1);
        __syncthreads();
        bf16x8 af[4], bfr[4];
#pragma unroll
        for (int mi = 0; mi < 4; ++mi)
            af[mi] = *(bf16x8*)(As + (wm + mi * 16 + l16) * 32 + quad * 8);
#pragma unroll
        for (int ni = 0; ni < 4; ++ni)
            bfr[ni] = *(bf16x8*)(Bs + (wn + ni * 16 + l16) * 32 + quad * 8);
#pragma unroll
        for (int mi = 0; mi < 4; ++mi)
#pragma unroll
            for (int ni = 0; ni < 4; ++ni)
                acc[mi][ni] =
                    __builtin_amdgcn_mfma_f32_16x16x32_bf16(af[mi], bfr[ni], acc[mi][ni], 0, 0, 0);
        __syncthreads();
    }
#pragma unroll
    for (int mi = 0; mi < 4; ++mi)
#pragma unroll
        for (int ni = 0; ni < 4; ++ni)
#pragma unroll
            for (int r = 0; r < 4; ++r) {
                int row = bm + wm + mi * 16 + quad * 4 + r;
                int col = bn + wn + ni * 16 + l16;
                if (col < N) {
                    if constexpr (OUTF32)
                        ((float*)Cp)[coff + (size_t)row * N + col] = acc[mi][ni][r];
                    else
                        ((bf16_t*)Cp)[coff + (size_t)row * N + col] = (bf16_t)acc[mi][ni][r];
                }
            }
}

// ---------------- build q ----------------
__global__ void k_build_q(bf16_t* __restrict__ q, const float* __restrict__ g,
                          const float* __restrict__ cosT, const float* __restrict__ sinT) {
    int wid = blockIdx.x * 4 + (threadIdx.x >> 6);
    int lane = threadIdx.x & 63;
    int row = wid >> 4, h = wid & 15;
    int t = row & 2047;
    bf16_t* p = q + (size_t)row * 2048 + h * 128;
    float x0 = (float)p[lane];
    float x1 = (float)p[64 + lane];
    float xp = (float)p[64 + (lane ^ 32)];
    float c = cosT[t * 64 + lane], s = sinT[t * 64 + lane];
    float rot = (lane < 32) ? -xp : xp;
    float y1 = x1 * c + rot * s;
    float ss = x0 * x0 + y1 * y1;
#pragma unroll
    for (int m = 32; m; m >>= 1) ss += __shfl_xor(ss, m);
    float scale = rsqrtf(ss / 128.f + 1e-6f);
    p[lane] = (bf16_t)(x0 * scale * g[lane]);
    p[64 + lane] = (bf16_t)(y1 * scale * g[64 + lane]);
}

// ---------------- build k ----------------
__global__ void k_build_k(const bf16_t* __restrict__ knope, const bf16_t* __restrict__ krope,
                          bf16_t* __restrict__ kout, const float* __restrict__ g,
                          const float* __restrict__ cosT, const float* __restrict__ sinT) {
    int wid = blockIdx.x * 4 + (threadIdx.x >> 6);
    int lane = threadIdx.x & 63;
    int row = wid >> 4, h = wid & 15;
    int t = row & 2047;
    float x0 = (float)knope[(size_t)row * 1024 + h * 64 + lane];
    float x1 = (float)krope[(size_t)row * 64 + lane];
    float xp = (float)krope[(size_t)row * 64 + (lane ^ 32)];
    float c = cosT[t * 64 + lane], s = sinT[t * 64 + lane];
    float rot = (lane < 32) ? -xp : xp;
    float y1 = x1 * c + rot * s;
    float ss = x0 * x0 + y1 * y1;
#pragma unroll
    for (int m = 32; m; m >>= 1) ss += __shfl_xor(ss, m);
    float scale = rsqrtf(ss / 128.f + 1e-6f);
    bf16_t* p = kout + (size_t)row * 2048 + h * 128;
    p[lane] = (bf16_t)(x0 * scale * g[lane]);
    p[64 + lane] = (bf16_t)(y1 * scale * g[64 + lane]);
}

// ---------------- flash attention + silu(gate), fixed-max softmax ----------------
// grid (T/128, B*H), 512 threads = 8 waves = 4 row-groups (32 q-rows) x 2-way split.
// Pair (wt,part): QK^T splits the s-axis, PV splits the d-axis -> each LDS B-frag read
// feeds 2 MFMAs (halves K/V LDS read amplification vs 16-row waves).
// Padded LDS strides: 136/72 give 2-lanes-per-bank on b128 column reads (free, m136);
// Ps stride 68 makes the scalar P-stores cover all 32 banks (was 4-way at 72).
// All inner-loop LDS addresses are one per-lane base + compile-time immediates (no XOR
// temps) and __launch_bounds__(512,2) caps at 256 VGPR: the R3 scratch-spill
// (WRITE_SIZE 227MB) cannot recur.
// q,k,gate,o layout [(b*2048+pos)*2048 + h*128 + d]; vT layout [b][h*128+d][t].
__global__ __launch_bounds__(512, 2) void k_attn(const bf16_t* __restrict__ q,
                                                 const bf16_t* __restrict__ k,
                                                 const bf16_t* __restrict__ vT,
                                                 const bf16_t* __restrict__ gate,
                                                 bf16_t* __restrict__ o) {
    __shared__ bf16_t Ks[64 * 136];   // [s][128 d +8]   17.4 KB
    __shared__ bf16_t Vt[128 * 72];   // [d][64 s +8]    18.4 KB
    __shared__ bf16_t Ps[128 * 68];   // [t][64 s +4]    17.4 KB
    const int qb = (int)gridDim.x - 1 - (int)blockIdx.x;  // long blocks first
    const int bh = blockIdx.y;
    const int b = bh >> 4, h = bh & 15;
    const int t0 = qb * 128;
    const int tid = threadIdx.x, lane = tid & 63, wv = tid >> 6;  // wv 0..7
    const int quad = lane >> 4, l16 = lane & 15;
    const int wt = wv >> 1;          // row-group 0..3
    const int part = wv & 1;         // s-half (QK) / d-half (PV)
    const int wrow = t0 + wt * 32;   // row-group's first q row

    // Q fragments in registers: 2 row-tiles x 4 k-slices
    bf16x8 aq[2][4];
#pragma unroll
    for (int mi = 0; mi < 2; ++mi) {
        const bf16_t* qp =
            q + ((size_t)(b * 2048 + wrow + mi * 16 + l16)) * 2048 + h * 128 + quad * 8;
#pragma unroll
        for (int kk = 0; kk < 4; ++kk) aq[mi][kk] = *(const bf16x8*)(qp + kk * 32);
    }
    f32x4 oacc[2][4] = {};           // [row-tile][d-tile within this wave's 64-d half]
    float l_i[2][4] = {};            // partial softmax denom over this wave's s-half

    // per-lane LDS bases (element units); all inner-loop offsets are immediates
    const int ksb = (part * 32 + l16) * 136 + quad * 8;           // QK B-read
    const int psb = (wt * 32 + quad * 4) * 68 + part * 32 + l16;  // P-store
    const int pab = (wt * 32 + l16) * 68 + quad * 8;              // PV A-read
    const int vvb = (part * 64 + l16) * 72 + quad * 8;            // PV B-read

    const bf16_t* vbase = vT + ((size_t)b * 2048 + (size_t)h * 128) * 2048;
    const bf16_t* kbase = k + ((size_t)b * 2048) * 2048 + h * 128;

    // staging indices (512 threads)
    const int krow = tid >> 4;         // 0..31 (+32)
    const int kcol = (tid & 15) * 8;
    const int kds = krow * 136 + kcol;
    const int vrow = tid >> 3;         // 0..63 (+64)
    const int vcol = (tid & 7) * 8;
    const int vds = vrow * 72 + vcol;

    const int nkb = 2 * qb + 2;  // key tiles 0 .. 2qb+1
    bf16x8 kreg0, kreg1, vreg0, vreg1;
    {
        kreg0 = *(const bf16x8*)(kbase + (size_t)krow * 2048 + kcol);
        kreg1 = *(const bf16x8*)(kbase + (size_t)(krow + 32) * 2048 + kcol);
        vreg0 = *(const bf16x8*)(vbase + (size_t)vrow * 2048 + vcol);
        vreg1 = *(const bf16x8*)(vbase + (size_t)(vrow + 64) * 2048 + vcol);
    }
    for (int kb = 0; kb < nkb; ++kb) {
        const int s0 = kb * 64;
        __syncthreads();  // prev iter done reading Ks/Vt
        *(bf16x8*)(Ks + kds) = kreg0;
        *(bf16x8*)(Ks + kds + 32 * 136) = kreg1;
        *(bf16x8*)(Vt + vds) = vreg0;
        *(bf16x8*)(Vt + vds + 64 * 72) = vreg1;
        __syncthreads();
        if (kb + 1 < nkb) {  // prefetch next tile; latency overlaps compute below
            const int sn = s0 + 64;
            kreg0 = *(const bf16x8*)(kbase + (size_t)(sn + krow) * 2048 + kcol);
            kreg1 = *(const bf16x8*)(kbase + (size_t)(sn + krow + 32) * 2048 + kcol);
            vreg0 = *(const bf16x8*)(vbase + (size_t)vrow * 2048 + sn + vcol);
            vreg1 = *(const bf16x8*)(vbase + (size_t)(vrow + 64) * 2048 + sn + vcol);
        }
        const bool active = (s0 <= wrow + 31);  // pair-uniform
        if (active) {
            // S = Q K^T : this wave's 32x32 quarter (s-half = part); ni-outer keeps
            // only one pair of f32x4 score regs live at a time
#pragma unroll
            for (int ni = 0; ni < 2; ++ni) {
                f32x4 sc2[2] = {{0.f, 0.f, 0.f, 0.f}, {0.f, 0.f, 0.f, 0.f}};
#pragma unroll
                for (int kk = 0; kk < 4; ++kk) {
                    bf16x8 bk = *(bf16x8*)(Ks + ksb + ni * (16 * 136) + kk * 32);
                    sc2[0] = __builtin_amdgcn_mfma_f32_16x16x32_bf16(aq[0][kk], bk, sc2[0], 0, 0, 0);
                    sc2[1] = __builtin_amdgcn_mfma_f32_16x16x32_bf16(aq[1][kk], bk, sc2[1], 0, 0, 0);
                }
                // fixed-max softmax: p = exp(s*SCALE - SMAX); no per-iter reductions
                const int scol = s0 + part * 32 + ni * 16 + l16;
#pragma unroll
                for (int mi = 0; mi < 2; ++mi) {
                    const int trowb = wrow + mi * 16 + quad * 4;
                    const bool dg = (s0 + part * 32 + 31) > trowb;
#pragma unroll
                    for (int r2 = 0; r2 < 4; ++r2) {
                        float pv = __expf(sc2[mi][r2] * SCALE_F - SMAX_F);
                        if (dg && scol > trowb + r2) pv = 0.f;
                        l_i[mi][r2] += pv;
                        Ps[psb + mi * (16 * 68) + r2 * 68 + ni * 16] = (bf16_t)pv;
                    }
                }
            }
        }
        __syncthreads();  // both halves of P ready (pair exchange)
        if (active) {
            // O += P V : full s range, this wave's 64-d half
#pragma unroll
            for (int kk = 0; kk < 2; ++kk) {
                bf16x8 ap0 = *(bf16x8*)(Ps + pab + kk * 32);
                bf16x8 ap1 = *(bf16x8*)(Ps + pab + 16 * 68 + kk * 32);
#pragma unroll
                for (int nd = 0; nd < 4; ++nd) {
                    bf16x8 bv = *(bf16x8*)(Vt + vvb + nd * (16 * 72) + kk * 32);
                    oacc[0][nd] = __builtin_amdgcn_mfma_f32_16x16x32_bf16(ap0, bv, oacc[0][nd], 0, 0, 0);
                    oacc[1][nd] = __builtin_amdgcn_mfma_f32_16x16x32_bf16(ap1, bv, oacc[1][nd], 0, 0, 0);
                }
            }
        }
    }
    // reduce partial l over the 16 lanes holding each row
#pragma unroll
    for (int m = 8; m; m >>= 1)
#pragma unroll
        for (int mi = 0; mi < 2; ++mi)
#pragma unroll
            for (int r2 = 0; r2 < 4; ++r2) l_i[mi][r2] += __shfl_xor(l_i[mi][r2], m);
    // exchange l between the s-halves via LDS (Ps is dead now)
    __syncthreads();
    float* lbuf = (float*)Ps;  // [2][128]
    if (l16 == 0) {
#pragma unroll
        for (int mi = 0; mi < 2; ++mi)
#pragma unroll
            for (int r2 = 0; r2 < 4; ++r2)
                lbuf[part * 128 + wt * 32 + mi * 16 + quad * 4 + r2] = l_i[mi][r2];
    }
    __syncthreads();
    // epilogue: normalize, silu(gate), store (this wave's 64-d half)
#pragma unroll
    for (int mi = 0; mi < 2; ++mi)
#pragma unroll
        for (int r2 = 0; r2 < 4; ++r2) {
            int row = wt * 32 + mi * 16 + quad * 4 + r2;
            float rl = 1.f / (lbuf[row] + lbuf[128 + row]);
            int trow = wrow + mi * 16 + quad * 4 + r2;
#pragma unroll
            for (int nd = 0; nd < 4; ++nd) {
                int d = part * 64 + nd * 16 + l16;
                size_t gi = ((size_t)(b * 2048 + trow)) * 2048 + h * 128 + d;
                float gt = (float)gate[gi];
                float sg = gt / (1.f + __expf(-gt));
                o[gi] = (bf16_t)((oacc[mi][nd][r2] * rl) * sg);
            }
        }
}

extern "C" void kernel_launch(void* const* d_in, const int* in_sizes, int n_in,
                              void* d_out, int out_size, void* d_ws, size_t ws_size,
                              hipStream_t stream) {
    const float* x         = (const float*)d_in[0];
    const float* w_q_down  = (const float*)d_in[1];
    const float* g_q_down  = (const float*)d_in[2];
    const float* w_q_up    = (const float*)d_in[3];
    const float* w_kv_down = (const float*)d_in[4];
    const float* g_kv_down = (const float*)d_in[5];
    const float* w_k_up    = (const float*)d_in[6];
    const float* w_v_up    = (const float*)d_in[7];
    const float* w_k_rope  = (const float*)d_in[8];
    const float* g_q       = (const float*)d_in[9];
    const float* g_k       = (const float*)d_in[10];
    const float* w_gate    = (const float*)d_in[11];
    const float* w_o       = (const float*)d_in[12];
    float* out = (float*)d_out;

    char* base = (char*)d_ws;
    size_t off = 0;
    auto alloc = [&](size_t bytes) -> void* {
        void* p = base + off;
        off = (off + bytes + 255) & ~(size_t)255;
        return p;
    };
    const size_t MT = 8192;  // B*T
    bf16_t* xb     = (bf16_t*)alloc(MT * 2048 * 2);
    bf16_t* wqd_t  = (bf16_t*)alloc((size_t)1024 * 2048 * 2);
    bf16_t* wqu_t  = (bf16_t*)alloc((size_t)2048 * 1024 * 2);
    bf16_t* wkvd_t = (bf16_t*)alloc((size_t)512 * 2048 * 2);
    bf16_t* wku_t  = (bf16_t*)alloc((size_t)1024 * 512 * 2);
    bf16_t* wvu_t  = (bf16_t*)alloc((size_t)2048 * 512 * 2);
    bf16_t* wkr_t  = (bf16_t*)alloc((size_t)64 * 2048 * 2);
    bf16_t* wg_t   = (bf16_t*)alloc((size_t)2048 * 2048 * 2);
    bf16_t* wo_t   = (bf16_t*)alloc((size_t)2048 * 2048 * 2);
    bf16_t* qc     = (bf16_t*)alloc(MT * 1024 * 2);
    bf16_t* ckv    = (bf16_t*)alloc(MT * 512 * 2);
    bf16_t* krope  = (bf16_t*)alloc(MT * 64 * 2);
    bf16_t* vT     = (bf16_t*)alloc(MT * 2048 * 2);  // [b][h*128+d][t]
    bf16_t* gbuf   = (bf16_t*)alloc(MT * 2048 * 2);
    float* cosT    = (float*)alloc((size_t)2048 * 64 * 4);
    float* sinT    = (float*)alloc((size_t)2048 * 64 * 4);
    bf16_t* knope = qc;              // qc dead after q_up GEMM
    bf16_t* qbuf  = (bf16_t*)d_out;  // d_out scratch until final GEMM
    bf16_t* kbuf  = (bf16_t*)d_out + MT * 2048;
    bf16_t* obuf  = xb;              // xb dead after all x@W GEMMs

    k_convert<<<dim3(16384), dim3(256), 0, stream>>>(x, xb, 16777216);
    k_transpose<<<dim3(32, 64), 256, 0, stream>>>(w_q_down, wqd_t, 2048, 1024);
    k_transpose<<<dim3(64, 32), 256, 0, stream>>>(w_q_up, wqu_t, 1024, 2048);
    k_transpose<<<dim3(16, 64), 256, 0, stream>>>(w_kv_down, wkvd_t, 2048, 512);
    k_transpose<<<dim3(32, 16), 256, 0, stream>>>(w_k_up, wku_t, 512, 1024);
    k_transpose<<<dim3(64, 16), 256, 0, stream>>>(w_v_up, wvu_t, 512, 2048);
    k_transpose<<<dim3(2, 64), 256, 0, stream>>>(w_k_rope, wkr_t, 2048, 64);
    k_transpose<<<dim3(64, 64), 256, 0, stream>>>(w_gate, wg_t, 2048, 2048);
    k_transpose<<<dim3(64, 64), 256, 0, stream>>>(w_o, wo_t, 2048, 2048);
    k_rope_tables<<<dim3(512), 256, 0, stream>>>(cosT, sinT);
    // q path
    k_gemm<0><<<dim3(8, 64), 256, 0, stream>>>(xb, wqd_t, qc, 8192, 1024, 2048, 0, 0, 0);
    k_rmsnorm<<<dim3(8192), 256, 0, stream>>>(qc, g_q_down, 1024);
    k_gemm<0><<<dim3(16, 64), 256, 0, stream>>>(qc, wqu_t, qbuf, 8192, 2048, 1024, 0, 0, 0);
    // kv path
    k_gemm<0><<<dim3(4, 64), 256, 0, stream>>>(xb, wkvd_t, ckv, 8192, 512, 2048, 0, 0, 0);
    k_rmsnorm<<<dim3(8192), 256, 0, stream>>>(ckv, g_kv_down, 512);
    k_gemm<0><<<dim3(8, 64), 256, 0, stream>>>(ckv, wku_t, knope, 8192, 1024, 512, 0, 0, 0);
    // V^T per batch: vT_b[hd][t] = wvu_t[hd][k] · ckv_b[t][k]
    k_gemm<0><<<dim3(16, 16, 4), 256, 0, stream>>>(wvu_t, ckv, vT, 2048, 2048, 512,
                                                   0, (size_t)2048 * 512, (size_t)2048 * 2048);
    k_gemm<0><<<dim3(1, 64), 256, 0, stream>>>(xb, wkr_t, krope, 8192, 64, 2048, 0, 0, 0);
    // gate
    k_gemm<0><<<dim3(16, 64), 256, 0, stream>>>(xb, wg_t, gbuf, 8192, 2048, 2048, 0, 0, 0);
    // assemble q/k
    k_build_q<<<dim3(32768), 256, 0, stream>>>(qbuf, g_q, cosT, sinT);
    k_build_k<<<dim3(32768), 256, 0, stream>>>(knope, krope, kbuf, g_k, cosT, sinT);
    // attention + silu(gate)
    k_attn<<<dim3(16, 64), 512, 0, stream>>>(qbuf, kbuf, vT, gbuf, obuf);
    // output projection
    k_gemm<1><<<dim3(16, 64), 256, 0, stream>>>(obuf, wo_t, out, 8192, 2048, 2048, 0, 0, 0);
}

// Round 5
// 766.909 us; speedup vs baseline: 1.3668x; 1.1713x over previous
//
#include <hip/hip_runtime.h>
#include <hip/hip_bf16.h>
#include <math.h>

typedef __bf16 bf16_t;
typedef __bf16 bf16x4 __attribute__((ext_vector_type(4)));
typedef __bf16 bf16x8 __attribute__((ext_vector_type(8)));
typedef float f32x4 __attribute__((ext_vector_type(4)));

#define SCALE_F 0.08838834764831845f  // 1/sqrt(128)
#define SMAX_F 14.0f                  // fixed softmax max: score <= sqrt(128)=11.32 (+bf16 margin)

// async global->LDS, 16B per lane; LDS dest = wave-uniform base + lane*16
#define GLOAD_LDS16(gp, lp)                                              \
    __builtin_amdgcn_global_load_lds(                                    \
        (const __attribute__((address_space(1))) void*)(gp),             \
        (__attribute__((address_space(3))) void*)(lp), 16, 0, 0)

// ---------------- fp32 -> bf16 convert (vectorized) ----------------
__global__ void k_convert(const float* __restrict__ in, bf16_t* __restrict__ out, int n) {
    int i = (blockIdx.x * 256 + threadIdx.x) * 4;
    if (i >= n) return;
    float4 f = *(const float4*)(in + i);
    out[i + 0] = (bf16_t)f.x;
    out[i + 1] = (bf16_t)f.y;
    out[i + 2] = (bf16_t)f.z;
    out[i + 3] = (bf16_t)f.w;
}

// ---------------- transpose + convert: w[K][N] -> wt[N][K] bf16 ----------------
__global__ void k_transpose(const float* __restrict__ w, bf16_t* __restrict__ wt, int K, int N) {
    __shared__ float tile[32][33];
    int n0 = blockIdx.x * 32, k0 = blockIdx.y * 32;
    int tx = threadIdx.x & 31, ty = threadIdx.x >> 5;  // 32x8
#pragma unroll
    for (int i = 0; i < 32; i += 8)
        tile[ty + i][tx] = w[(size_t)(k0 + ty + i) * N + (n0 + tx)];
    __syncthreads();
#pragma unroll
    for (int i = 0; i < 32; i += 8)
        wt[(size_t)(n0 + ty + i) * K + (k0 + tx)] = (bf16_t)tile[tx][ty + i];
}

// ---------------- rope tables ----------------
__global__ void k_rope_tables(float* __restrict__ cosT, float* __restrict__ sinT) {
    int idx = blockIdx.x * 256 + threadIdx.x;  // t*64 + i
    int t = idx >> 6, i = idx & 63;
    float invf = powf(10000.f, -(float)(i & 31) / 32.f);
    float ang = (float)t * invf;
    float s, c;
    sincosf(ang, &s, &c);
    cosT[idx] = c;
    sinT[idx] = s;
}

// ---------------- row-wise rmsnorm, in-place bf16, fp32 gain ----------------
__global__ void k_rmsnorm(bf16_t* __restrict__ x, const float* __restrict__ g, int C) {
    bf16_t* p = x + (size_t)blockIdx.x * C;
    float ss = 0.f;
    for (int i = threadIdx.x; i < C; i += 256) {
        float v = (float)p[i];
        ss += v * v;
    }
#pragma unroll
    for (int m = 32; m; m >>= 1) ss += __shfl_xor(ss, m);
    __shared__ float red[4];
    if ((threadIdx.x & 63) == 0) red[threadIdx.x >> 6] = ss;
    __syncthreads();
    float tot = red[0] + red[1] + red[2] + red[3];
    float scale = rsqrtf(tot / (float)C + 1e-6f);
    for (int i = threadIdx.x; i < C; i += 256)
        p[i] = (bf16_t)((float)p[i] * scale * g[i]);
}

// ---------------- GEMM (m97 structure, BK=64): C[M][N] = A[M][K] @ Bt[N][K]^T ------
// Two m97-style 32-wide sub-buffers per barrier pair: same LDS read patterns as the
// proven 874-TF kernel, but one barrier pair per K=64 (halves barrier/vmcnt drains).
template <int OUTF32>
__global__ __launch_bounds__(256) void k_gemm(const bf16_t* __restrict__ A,
                                              const bf16_t* __restrict__ Bt,
                                              void* __restrict__ Cp, int M, int N, int K,
                                              size_t sA, size_t sB, size_t sC) {
    __shared__ bf16_t As[2][128 * 32];
    __shared__ bf16_t Bs[2][128 * 32];
    A += (size_t)blockIdx.z * sA;
    Bt += (size_t)blockIdx.z * sB;
    const size_t coff = (size_t)blockIdx.z * sC;
    const int bm = blockIdx.y * 128, bn = blockIdx.x * 128;
    const int tid = threadIdx.x, lane = tid & 63, wv = tid >> 6;
    const int quad = lane >> 4, l16 = lane & 15;
    const int wm = (wv >> 1) * 64, wn = (wv & 1) * 64;
    f32x4 acc[4][4] = {};
    const int sr0 = wv * 32 + (lane >> 2);
    const int scc = (lane & 3) * 8;
    const int lo0 = (wv * 2) * 512, lo1 = (wv * 2 + 1) * 512;
    const bool bok0 = (bn + sr0) < N;
    const bool bok1 = (bn + sr0 + 16) < N;
    for (int k0 = 0; k0 < K; k0 += 64) {
        const bf16_t* gA = A + (size_t)(bm + sr0) * K + k0 + scc;
        const bf16_t* gB = Bt + (size_t)(bn + sr0) * K + k0 + scc;
        GLOAD_LDS16(gA, As[0] + lo0);
        GLOAD_LDS16(gA + (size_t)16 * K, As[0] + lo1);
        GLOAD_LDS16(gA + 32, As[1] + lo0);
        GLOAD_LDS16(gA + (size_t)16 * K + 32, As[1] + lo1);
        if (bok0) {
            GLOAD_LDS16(gB, Bs[0] + lo0);
            GLOAD_LDS16(gB + 32, Bs[1] + lo0);
        }
        if (bok1) {
            GLOAD_LDS16(gB + (size_t)16 * K, Bs[0] + lo1);
            GLOAD_LDS16(gB + (size_t)16 * K + 32, Bs[1] + lo1);
        }
        __syncthreads();
#pragma unroll
        for (int hf = 0; hf < 2; ++hf) {
            bf16x8 af[4], bfr[4];
#pragma unroll
            for (int mi = 0; mi < 4; ++mi)
                af[mi] = *(bf16x8*)(As[hf] + (wm + mi * 16 + l16) * 32 + quad * 8);
#pragma unroll
            for (int ni = 0; ni < 4; ++ni)
                bfr[ni] = *(bf16x8*)(Bs[hf] + (wn + ni * 16 + l16) * 32 + quad * 8);
#pragma unroll
            for (int mi = 0; mi < 4; ++mi)
#pragma unroll
                for (int ni = 0; ni < 4; ++ni)
                    acc[mi][ni] = __builtin_amdgcn_mfma_f32_16x16x32_bf16(af[mi], bfr[ni],
                                                                          acc[mi][ni], 0, 0, 0);
        }
        __syncthreads();
    }
#pragma unroll
    for (int mi = 0; mi < 4; ++mi)
#pragma unroll
        for (int ni = 0; ni < 4; ++ni)
#pragma unroll
            for (int r = 0; r < 4; ++r) {
                int row = bm + wm + mi * 16 + quad * 4 + r;
                int col = bn + wn + ni * 16 + l16;
                if (col < N) {
                    if constexpr (OUTF32)
                        ((float*)Cp)[coff + (size_t)row * N + col] = acc[mi][ni][r];
                    else
                        ((bf16_t*)Cp)[coff + (size_t)row * N + col] = (bf16_t)acc[mi][ni][r];
                }
            }
}

// ---------------- build q ----------------
__global__ void k_build_q(bf16_t* __restrict__ q, const float* __restrict__ g,
                          const float* __restrict__ cosT, const float* __restrict__ sinT) {
    int wid = blockIdx.x * 4 + (threadIdx.x >> 6);
    int lane = threadIdx.x & 63;
    int row = wid >> 4, h = wid & 15;
    int t = row & 2047;
    bf16_t* p = q + (size_t)row * 2048 + h * 128;
    float x0 = (float)p[lane];
    float x1 = (float)p[64 + lane];
    float xp = (float)p[64 + (lane ^ 32)];
    float c = cosT[t * 64 + lane], s = sinT[t * 64 + lane];
    float rot = (lane < 32) ? -xp : xp;
    float y1 = x1 * c + rot * s;
    float ss = x0 * x0 + y1 * y1;
#pragma unroll
    for (int m = 32; m; m >>= 1) ss += __shfl_xor(ss, m);
    float scale = rsqrtf(ss / 128.f + 1e-6f);
    p[lane] = (bf16_t)(x0 * scale * g[lane]);
    p[64 + lane] = (bf16_t)(y1 * scale * g[64 + lane]);
}

// ---------------- build k ----------------
__global__ void k_build_k(const bf16_t* __restrict__ knope, const bf16_t* __restrict__ krope,
                          bf16_t* __restrict__ kout, const float* __restrict__ g,
                          const float* __restrict__ cosT, const float* __restrict__ sinT) {
    int wid = blockIdx.x * 4 + (threadIdx.x >> 6);
    int lane = threadIdx.x & 63;
    int row = wid >> 4, h = wid & 15;
    int t = row & 2047;
    float x0 = (float)knope[(size_t)row * 1024 + h * 64 + lane];
    float x1 = (float)krope[(size_t)row * 64 + lane];
    float xp = (float)krope[(size_t)row * 64 + (lane ^ 32)];
    float c = cosT[t * 64 + lane], s = sinT[t * 64 + lane];
    float rot = (lane < 32) ? -xp : xp;
    float y1 = x1 * c + rot * s;
    float ss = x0 * x0 + y1 * y1;
#pragma unroll
    for (int m = 32; m; m >>= 1) ss += __shfl_xor(ss, m);
    float scale = rsqrtf(ss / 128.f + 1e-6f);
    bf16_t* p = kout + (size_t)row * 2048 + h * 128;
    p[lane] = (bf16_t)(x0 * scale * g[lane]);
    p[64 + lane] = (bf16_t)(y1 * scale * g[64 + lane]);
}

// ---------------- flash attention + silu(gate), swapped-QK, no P-LDS --------------
// grid (T/128, B*H), 512 threads = 8 independent waves, wave wv owns q-rows
// [t0+wv*16, +16). 2 barriers/tile (staging only) -> waves drift phases freely.
// QK^T computed SWAPPED: mfma(A=K, B=Q). Fragment reads are byte-identical to the
// normal orientation, but the scores land transposed: lane(quad,l16) holds
// S[s = s0+16ni+4*quad+r][t = wrow+l16]. Softmax is then per-lane; P never touches
// LDS: the PV A-fragment is built in-register (8 casts). The PV k-order mismatch is
// absorbed by storing V in LDS with s-bit-permuted positions p = (s4? no):
//   s = 32kk+16h+4q+r  ->  p = 32kk+8q+4h+r   (swap h and q bit-fields)
// so A (P) and B (V) contract k in the same permuted order (sum unchanged).
// l_i: deferred per-lane partial + 2 shfl_xor after the loop; tiny lbuf for the
// quad-transpose broadcast (wave-private rows, no barrier).
// q,k,gate,o layout [(b*2048+pos)*2048 + h*128 + d]; vT layout [b][h*128+d][t].
__global__ __launch_bounds__(512, 4) void k_attn(const bf16_t* __restrict__ q,
                                                 const bf16_t* __restrict__ k,
                                                 const bf16_t* __restrict__ vT,
                                                 const bf16_t* __restrict__ gate,
                                                 bf16_t* __restrict__ o) {
    __shared__ bf16_t Ks[64 * 136];   // [s][128 d +8]       17.4 KB
    __shared__ bf16_t Vt[128 * 72];   // [d][64 s-perm +8]   18.4 KB
    __shared__ float lbuf[128];       // l broadcast          0.5 KB
    const int qb = (int)gridDim.x - 1 - (int)blockIdx.x;  // long blocks first
    const int bh = blockIdx.y;
    const int b = bh >> 4, h = bh & 15;
    const int t0 = qb * 128;
    const int tid = threadIdx.x, lane = tid & 63, wv = tid >> 6;  // wv 0..7
    const int quad = lane >> 4, l16 = lane & 15;
    const int wrow = t0 + wv * 16;  // wave's first q row

    // Q B-fragments in registers (n = l16 -> row t = wrow+l16, k = quad*8+j)
    bf16x8 aq[4];
    {
        const bf16_t* qp = q + ((size_t)(b * 2048 + wrow + l16)) * 2048 + h * 128 + quad * 8;
#pragma unroll
        for (int kk = 0; kk < 4; ++kk) aq[kk] = *(const bf16x8*)(qp + kk * 32);
    }
    f32x4 oacc[8] = {};
    float l_lane = 0.f;  // per-lane partial softmax denom (this lane's s-subset)

    const bf16_t* vbase = vT + ((size_t)b * 2048 + (size_t)h * 128) * 2048;
    const bf16_t* kbase = k + ((size_t)b * 2048) * 2048 + h * 128;

    // staging indices (512 threads)
    const int krow = tid >> 4;         // 0..31 (+32)
    const int kcol = (tid & 15) * 8;
    const int kds = krow * 136 + kcol;
    const int vrow = tid >> 3;         // 0..63 (+64)
    const int vcol = (tid & 7) * 8;    // 8 consecutive s
    const int a8 = tid & 7;            // s-chunk index: s_loc = 8*a8 + e
    // permuted base positions for the two b64 halves of this chunk
    const int pb0 = (a8 >> 2) * 32 + (a8 & 1) * 16 + ((a8 >> 1) & 1) * 4;
    const int vds = vrow * 72 + pb0;   // e0..3 at +0, e4..7 at +8

    const int nkb = 2 * qb + 2;  // key tiles 0 .. 2qb+1
    bf16x8 kreg0, kreg1, vreg0, vreg1;
    {
        kreg0 = *(const bf16x8*)(kbase + (size_t)krow * 2048 + kcol);
        kreg1 = *(const bf16x8*)(kbase + (size_t)(krow + 32) * 2048 + kcol);
        vreg0 = *(const bf16x8*)(vbase + (size_t)vrow * 2048 + vcol);
        vreg1 = *(const bf16x8*)(vbase + (size_t)(vrow + 64) * 2048 + vcol);
    }
    for (int kb = 0; kb < nkb; ++kb) {
        const int s0 = kb * 64;
        __syncthreads();  // prev iter done reading Ks/Vt
        *(bf16x8*)(Ks + kds) = kreg0;
        *(bf16x8*)(Ks + kds + 32 * 136) = kreg1;
        {
            bf16x4 v0lo = __builtin_shufflevector(vreg0, vreg0, 0, 1, 2, 3);
            bf16x4 v0hi = __builtin_shufflevector(vreg0, vreg0, 4, 5, 6, 7);
            bf16x4 v1lo = __builtin_shufflevector(vreg1, vreg1, 0, 1, 2, 3);
            bf16x4 v1hi = __builtin_shufflevector(vreg1, vreg1, 4, 5, 6, 7);
            *(bf16x4*)(Vt + vds) = v0lo;
            *(bf16x4*)(Vt + vds + 8) = v0hi;
            *(bf16x4*)(Vt + vds + 64 * 72) = v1lo;
            *(bf16x4*)(Vt + vds + 64 * 72 + 8) = v1hi;
        }
        __syncthreads();
        if (kb + 1 < nkb) {  // prefetch next tile; latency overlaps compute below
            const int sn = s0 + 64;
            kreg0 = *(const bf16x8*)(kbase + (size_t)(sn + krow) * 2048 + kcol);
            kreg1 = *(const bf16x8*)(kbase + (size_t)(sn + krow + 32) * 2048 + kcol);
            vreg0 = *(const bf16x8*)(vbase + (size_t)vrow * 2048 + sn + vcol);
            vreg1 = *(const bf16x8*)(vbase + (size_t)(vrow + 64) * 2048 + sn + vcol);
        }
        if (s0 > wrow + 15) continue;  // wave fully above diagonal (wave-uniform skip)
        // S^T = K Q^T : sc[ni] lane(quad,l16) = S[s0+16ni+4quad+r][wrow+l16]
        f32x4 sc[4] = {};
#pragma unroll
        for (int ni = 0; ni < 4; ++ni)
#pragma unroll
            for (int kk = 0; kk < 4; ++kk) {
                bf16x8 ak = *(bf16x8*)(Ks + (ni * 16 + l16) * 136 + kk * 32 + quad * 8);
                sc[ni] = __builtin_amdgcn_mfma_f32_16x16x32_bf16(ak, aq[kk], sc[ni], 0, 0, 0);
            }
        // fixed-max softmax + causal mask, fully in-register
        const int tq = wrow + l16;
#pragma unroll
        for (int ni = 0; ni < 4; ++ni) {
            const int sb = s0 + ni * 16 + quad * 4;
#pragma unroll
            for (int r2 = 0; r2 < 4; ++r2) {
                float pv = __expf(sc[ni][r2] * SCALE_F - SMAX_F);
                if (sb + r2 > tq) pv = 0.f;
                sc[ni][r2] = pv;
                l_lane += pv;
            }
        }
        // build PV A-fragments in-register: k-slot (quad,j) <-> s = 32kk+16(j>>2)+4quad+(j&3)
        bf16x8 pa0, pa1;
#pragma unroll
        for (int r2 = 0; r2 < 4; ++r2) {
            pa0[r2] = (bf16_t)sc[0][r2];
            pa0[4 + r2] = (bf16_t)sc[1][r2];
            pa1[r2] = (bf16_t)sc[2][r2];
            pa1[4 + r2] = (bf16_t)sc[3][r2];
        }
        // O += P V (V read in the same permuted k-order)
#pragma unroll
        for (int nd = 0; nd < 8; ++nd) {
            bf16x8 bv = *(bf16x8*)(Vt + (nd * 16 + l16) * 72 + quad * 8);
            oacc[nd] = __builtin_amdgcn_mfma_f32_16x16x32_bf16(pa0, bv, oacc[nd], 0, 0, 0);
        }
#pragma unroll
        for (int nd = 0; nd < 8; ++nd) {
            bf16x8 bv = *(bf16x8*)(Vt + (nd * 16 + l16) * 72 + 32 + quad * 8);
            oacc[nd] = __builtin_amdgcn_mfma_f32_16x16x32_bf16(pa1, bv, oacc[nd], 0, 0, 0);
        }
    }
    // finish l: sum the 4 quads holding the same t, broadcast via wave-private lbuf
    l_lane += __shfl_xor(l_lane, 16);
    l_lane += __shfl_xor(l_lane, 32);
    if (quad == 0) lbuf[wv * 16 + l16] = l_lane;
    float rl[4];
#pragma unroll
    for (int r2 = 0; r2 < 4; ++r2) rl[r2] = 1.f / lbuf[wv * 16 + quad * 4 + r2];
    // epilogue: normalize, silu(gate), store
#pragma unroll
    for (int nd = 0; nd < 8; ++nd) {
        int d = nd * 16 + l16;
#pragma unroll
        for (int r2 = 0; r2 < 4; ++r2) {
            int trow = wrow + quad * 4 + r2;
            size_t gi = ((size_t)(b * 2048 + trow)) * 2048 + h * 128 + d;
            float gt = (float)gate[gi];
            float sg = gt / (1.f + __expf(-gt));
            o[gi] = (bf16_t)((oacc[nd][r2] * rl[r2]) * sg);
        }
    }
}

extern "C" void kernel_launch(void* const* d_in, const int* in_sizes, int n_in,
                              void* d_out, int out_size, void* d_ws, size_t ws_size,
                              hipStream_t stream) {
    const float* x         = (const float*)d_in[0];
    const float* w_q_down  = (const float*)d_in[1];
    const float* g_q_down  = (const float*)d_in[2];
    const float* w_q_up    = (const float*)d_in[3];
    const float* w_kv_down = (const float*)d_in[4];
    const float* g_kv_down = (const float*)d_in[5];
    const float* w_k_up    = (const float*)d_in[6];
    const float* w_v_up    = (const float*)d_in[7];
    const float* w_k_rope  = (const float*)d_in[8];
    const float* g_q       = (const float*)d_in[9];
    const float* g_k       = (const float*)d_in[10];
    const float* w_gate    = (const float*)d_in[11];
    const float* w_o       = (const float*)d_in[12];
    float* out = (float*)d_out;

    char* base = (char*)d_ws;
    size_t off = 0;
    auto alloc = [&](size_t bytes) -> void* {
        void* p = base + off;
        off = (off + bytes + 255) & ~(size_t)255;
        return p;
    };
    const size_t MT = 8192;  // B*T
    bf16_t* xb     = (bf16_t*)alloc(MT * 2048 * 2);
    bf16_t* wqd_t  = (bf16_t*)alloc((size_t)1024 * 2048 * 2);
    bf16_t* wqu_t  = (bf16_t*)alloc((size_t)2048 * 1024 * 2);
    bf16_t* wkvd_t = (bf16_t*)alloc((size_t)512 * 2048 * 2);
    bf16_t* wku_t  = (bf16_t*)alloc((size_t)1024 * 512 * 2);
    bf16_t* wvu_t  = (bf16_t*)alloc((size_t)2048 * 512 * 2);
    bf16_t* wkr_t  = (bf16_t*)alloc((size_t)64 * 2048 * 2);
    bf16_t* wg_t   = (bf16_t*)alloc((size_t)2048 * 2048 * 2);
    bf16_t* wo_t   = (bf16_t*)alloc((size_t)2048 * 2048 * 2);
    bf16_t* qc     = (bf16_t*)alloc(MT * 1024 * 2);
    bf16_t* ckv    = (bf16_t*)alloc(MT * 512 * 2);
    bf16_t* krope  = (bf16_t*)alloc(MT * 64 * 2);
    bf16_t* vT     = (bf16_t*)alloc(MT * 2048 * 2);  // [b][h*128+d][t]
    bf16_t* gbuf   = (bf16_t*)alloc(MT * 2048 * 2);
    float* cosT    = (float*)alloc((size_t)2048 * 64 * 4);
    float* sinT    = (float*)alloc((size_t)2048 * 64 * 4);
    bf16_t* knope = qc;              // qc dead after q_up GEMM
    bf16_t* qbuf  = (bf16_t*)d_out;  // d_out scratch until final GEMM
    bf16_t* kbuf  = (bf16_t*)d_out + MT * 2048;
    bf16_t* obuf  = xb;              // xb dead after all x@W GEMMs

    k_convert<<<dim3(16384), dim3(256), 0, stream>>>(x, xb, 16777216);
    k_transpose<<<dim3(32, 64), 256, 0, stream>>>(w_q_down, wqd_t, 2048, 1024);
    k_transpose<<<dim3(64, 32), 256, 0, stream>>>(w_q_up, wqu_t, 1024, 2048);
    k_transpose<<<dim3(16, 64), 256, 0, stream>>>(w_kv_down, wkvd_t, 2048, 512);
    k_transpose<<<dim3(32, 16), 256, 0, stream>>>(w_k_up, wku_t, 512, 1024);
    k_transpose<<<dim3(64, 16), 256, 0, stream>>>(w_v_up, wvu_t, 512, 2048);
    k_transpose<<<dim3(2, 64), 256, 0, stream>>>(w_k_rope, wkr_t, 2048, 64);
    k_transpose<<<dim3(64, 64), 256, 0, stream>>>(w_gate, wg_t, 2048, 2048);
    k_transpose<<<dim3(64, 64), 256, 0, stream>>>(w_o, wo_t, 2048, 2048);
    k_rope_tables<<<dim3(512), 256, 0, stream>>>(cosT, sinT);
    // q path
    k_gemm<0><<<dim3(8, 64), 256, 0, stream>>>(xb, wqd_t, qc, 8192, 1024, 2048, 0, 0, 0);
    k_rmsnorm<<<dim3(8192), 256, 0, stream>>>(qc, g_q_down, 1024);
    k_gemm<0><<<dim3(16, 64), 256, 0, stream>>>(qc, wqu_t, qbuf, 8192, 2048, 1024, 0, 0, 0);
    // kv path
    k_gemm<0><<<dim3(4, 64), 256, 0, stream>>>(xb, wkvd_t, ckv, 8192, 512, 2048, 0, 0, 0);
    k_rmsnorm<<<dim3(8192), 256, 0, stream>>>(ckv, g_kv_down, 512);
    k_gemm<0><<<dim3(8, 64), 256, 0, stream>>>(ckv, wku_t, knope, 8192, 1024, 512, 0, 0, 0);
    // V^T per batch: vT_b[hd][t] = wvu_t[hd][k] · ckv_b[t][k]
    k_gemm<0><<<dim3(16, 16, 4), 256, 0, stream>>>(wvu_t, ckv, vT, 2048, 2048, 512,
                                                   0, (size_t)2048 * 512, (size_t)2048 * 2048);
    k_gemm<0><<<dim3(1, 64), 256, 0, stream>>>(xb, wkr_t, krope, 8192, 64, 2048, 0, 0, 0);
    // gate
    k_gemm<0><<<dim3(16, 64), 256, 0, stream>>>(xb, wg_t, gbuf, 8192, 2048, 2048, 0, 0, 0);
    // assemble q/k
    k_build_q<<<dim3(32768), 256, 0, stream>>>(qbuf, g_q, cosT, sinT);
    k_build_k<<<dim3(32768), 256, 0, stream>>>(knope, krope, kbuf, g_k, cosT, sinT);
    // attention + silu(gate)
    k_attn<<<dim3(16, 64), 512, 0, stream>>>(qbuf, kbuf, vT, gbuf, obuf);
    // output projection
    k_gemm<1><<<dim3(16, 64), 256, 0, stream>>>(obuf, wo_t, out, 8192, 2048, 2048, 0, 0, 0);
}